// Round 10
// baseline (586.255 us; speedup 1.0000x reference)
//
#include <hip/hip_runtime.h>

// Sparse-conv encoder, bf16-MFMA implicit-GEMM.
// Round-19 change: LDS BAND STAGING. Rounds 5-9 proved the 32-ch convs are
// pinned at 55-63us by gathered-line traffic (27 x n1 x 64B ~= 513MB at
// ~8TB/s random-line rate), schedule-invariant. But km_in rows are ASCENDING
// (coords lex-sorted) and the 27 offsets form 3 CONTIGUOUS index bands (one
// per dx; dy/dz shift by +-few). Per 64-row tile the input union is ~3x90
// contiguous rows (~17KB): stage each band into LDS coalesced (XOR-swizzled
// slots), gather A-fragments via ds_read_b128. Bands wider than CAP=160 fall
// back per-step to the old global gather (correctness-guaranteed). M-split
// (wave = 16-row subtile) is safe now: gathers are LDS-latency.
// down keeps the K-split tab path (kmd unsorted); first conv unchanged.

#define TPB 256

typedef __attribute__((ext_vector_type(8))) short short8;
typedef __attribute__((ext_vector_type(4))) float floatx4;

static __device__ __forceinline__ unsigned short f2b(float f) {
    union { float f; unsigned u; } v; v.f = f;
    unsigned r = v.u + 0x7fffu + ((v.u >> 16) & 1u);   // RNE
    return (unsigned short)(r >> 16);
}
static __device__ __forceinline__ float b2f(unsigned short h) {
    union { unsigned u; float f; } v; v.u = ((unsigned)h) << 16;
    return v.f;
}

// ---------- CSR window boundaries ----------
// st[k][tile] = lower_bound(km_out[k], min(tile*64, n)), tile in [0, T].
__global__ void search_k(const int* __restrict__ km0_out,
                         const int* __restrict__ km1_out,
                         long long P0, long long P1, int T0, int T1,
                         int n0, int n1,
                         int* __restrict__ st0, int* __restrict__ st1) {
    unsigned t = blockIdx.x * blockDim.x + threadIdx.x;
    unsigned N0 = 27u * (unsigned)(T0 + 1);
    unsigned N1 = 27u * (unsigned)(T1 + 1);
    const int* row;
    long long P;
    int th;
    int* dst;
    if (t < N0) {
        unsigned k = t / (unsigned)(T0 + 1), tile = t - k * (unsigned)(T0 + 1);
        row = km0_out + (long long)k * P0; P = P0;
        long long thr = (long long)tile * 64;
        th = thr < n0 ? (int)thr : n0;
        dst = st0 + t;
    } else {
        t -= N0;
        if (t >= N1) return;
        unsigned k = t / (unsigned)(T1 + 1), tile = t - k * (unsigned)(T1 + 1);
        row = km1_out + (long long)k * P1; P = P1;
        long long thr = (long long)tile * 64;
        th = thr < n1 ? (int)thr : n1;
        dst = st1 + t;
    }
    long long lo = 0, hi = P;
    while (lo < hi) {
        long long mid = (lo + hi) >> 1;
        if (row[mid] < th) lo = mid + 1; else hi = mid;
    }
    *dst = (int)lo;
}

static __device__ __forceinline__ void pack16_elem(
    const float* __restrict__ W, unsigned short* __restrict__ Wp,
    int t, int COUT, int Ksrc) {
    int j = t & 7;
    int r = t >> 3;
    int n = r % COUT; r /= COUT;
    int q = r & 3;
    int k2 = r >> 2;
    int ks = 2 * k2 + (q >> 1);
    int cin = (q & 1) * 8 + j;
    float v = (ks < Ksrc) ? W[(ks * 16 + cin) * COUT + n] : 0.f;
    Wp[t] = f2b(v);
}

// one dispatch: td scatter (kmd unsorted -> tab path) + all weight packing
// + zero pad rows of the 5 bf16 feature buffers
__global__ void prep_all(const int* __restrict__ kmd_in, const int* __restrict__ kmd_out,
                         int* __restrict__ td, unsigned Pd, unsigned rc1, unsigned n1,
                         const float* __restrict__ W_pre, const float* __restrict__ W_down,
                         const float* __restrict__ W_r0, const float* __restrict__ W_r1,
                         const float* __restrict__ W_fin,
                         unsigned short* __restrict__ wp_pre, unsigned short* __restrict__ wp_down,
                         unsigned short* __restrict__ wp_r0, unsigned short* __restrict__ wp_r1,
                         unsigned short* __restrict__ wp_fin,
                         unsigned short* p0, unsigned short* p1, unsigned short* p2,
                         unsigned short* p3, unsigned short* p4) {
    unsigned tu = blockIdx.x * blockDim.x + threadIdx.x;
    unsigned Nd = 8u * Pd;
    if (tu < Nd) {                    // td scatter: 1 entry/thread, guarded store
        int o = kmd_out[tu];
        int i = kmd_in[tu];
        if ((unsigned)o < n1) td[(tu / Pd) * rc1 + (unsigned)o] = i;
        return;
    }
    int t = (int)(tu - Nd);
    if (t < 7168) { pack16_elem(W_pre, wp_pre, t, 16, 27); return; }
    t -= 7168;
    if (t < 4096) { pack16_elem(W_down, wp_down, t, 32, 8); return; }
    t -= 4096;
    if (t < 27648) {   // W (27,32,32): Wp[((k*4+q)*32+n)*8+j] = W[k][q*8+j][n]
        int j = t & 7, n = (t >> 3) & 31, q = (t >> 8) & 3, k = t >> 10;
        wp_r0[t] = f2b(W_r0[(k * 32 + q * 8 + j) * 32 + n]); return;
    }
    t -= 27648;
    if (t < 27648) {
        int j = t & 7, n = (t >> 3) & 31, q = (t >> 8) & 3, k = t >> 10;
        wp_r1[t] = f2b(W_r1[(k * 32 + q * 8 + j) * 32 + n]); return;
    }
    t -= 27648;
    if (t < 27648) {
        int j = t & 7, n = (t >> 3) & 31, q = (t >> 8) & 3, k = t >> 10;
        wp_fin[t] = f2b(W_fin[(k * 32 + q * 8 + j) * 32 + n]); return;
    }
    t -= 27648;
    if (t < 16) p0[t] = 0;
    else if (t < 32) p1[t - 16] = 0;
    else if (t < 64) p2[t - 32] = 0;
    else if (t < 96) p3[t - 64] = 0;
    else if (t < 128) p4[t - 96] = 0;
}

// first conv: C_IN=1 -> 16, K=27, relu; CSR idx build into LDS (256 rows/
// block). Writes f32 (cached out) + bf16 copy.
__global__ __launch_bounds__(TPB) void conv_first_k(
    const float* __restrict__ xin, const float* __restrict__ W,
    const float* __restrict__ b,
    const int* __restrict__ km_in, const int* __restrict__ km_out,
    const int* __restrict__ st, long long P, int T,
    int n0, float* __restrict__ outf, unsigned short* __restrict__ outb) {
    __shared__ int lidx[27][256];
    const int blk = (int)blockIdx.x;
    const int j0 = blk * 256;
    const int wv = (int)(threadIdx.x >> 6), lane = (int)(threadIdx.x & 63);
    const int ta = 4 * blk;
    const int tb = (4 * blk + 4 < T) ? 4 * blk + 4 : T;
    for (int r = wv; r < 27; r += 4) {
#pragma unroll
        for (int i = 0; i < 4; ++i) lidx[r][lane + 64 * i] = n0;   // pad
        int s = st[r * (T + 1) + ta];
        int e = st[r * (T + 1) + tb];
        for (int i = s + lane; i < e; i += 64) {
            int o = km_out[(long long)r * P + i];
            lidx[r][o - j0] = km_in[(long long)r * P + i];
        }
    }
    __syncthreads();
    int j = j0 + (int)threadIdx.x;
    if (j >= n0) return;
    float acc[16];
#pragma unroll
    for (int c = 0; c < 16; ++c) acc[c] = b[c];
#pragma unroll
    for (int k = 0; k < 27; ++k) {
        int idx = lidx[k][threadIdx.x];
        bool ok = idx < n0;
        int cidx = ok ? idx : 0;
        float v = xin[cidx];
        v = ok ? v : 0.f;
        const float* Wk = W + k * 16;
#pragma unroll
        for (int c = 0; c < 16; ++c) acc[c] = fmaf(v, Wk[c], acc[c]);
    }
    float* orow = outf + (long long)j * 16;
    unsigned short* brow = outb + (long long)j * 16;
#pragma unroll
    for (int c = 0; c < 16; ++c) {
        float v = fmaxf(acc[c], 0.f);
        orow[c] = v;
        brow[c] = f2b(v);
    }
}

// ---------- LDS-band conv (CSR, sorted km rows) ----------
// Block = one 64-row tile, M-split (wave wv owns subtile wv). The 27 offsets
// form 3 contiguous index bands (g = k/9); each band's [min,max] row range is
// staged into LDS (XOR-swizzled 16B slots). Bands wider than CAP fall back
// per-step to global gather. lidx[k][slot] = LDS row (banded) or global row
// (fallback); pad = ZROW / n_in to match the step's mode.
template <int CIN, int COUT, int STEPS, bool RELU, bool RES, bool WF32, bool WB16>
__global__ __launch_bounds__(TPB, 4) void conv_band(
    const unsigned short* __restrict__ xb,   // (n_in+1, CIN) bf16, pad row zero
    const unsigned short* __restrict__ Wp,
    const float* __restrict__ bias,
    const int* __restrict__ km_in, const int* __restrict__ km_out,
    const int* __restrict__ st, int T, long long P,
    int n_in, int n_out, long long ntiles,
    const unsigned short* __restrict__ resb,
    float* __restrict__ outf, unsigned short* __restrict__ outb) {
    constexpr int NT = COUT / 16;
    constexpr int NK = (CIN == 16) ? 2 * STEPS : STEPS;  // lidx rows (28/27)
    constexpr int NS16 = (CIN * 2) / 16;                 // 16B slots/row: 4/2
    constexpr int CAP = 160;
    constexpr int ZROW = 3 * CAP;                        // zeroed pad row
    __shared__ short8 bandmem8[((3 * CAP + 1) * CIN) / 8];
    unsigned short* bandmem = (unsigned short*)bandmem8;
    __shared__ int lidx[NK * 64];
    __shared__ int blo[3], bhi[3];
    __shared__ int fbstep[STEPS];

    // bijective XCD swizzle: gridDim.x % 8 == 0
    int runs = (int)gridDim.x >> 3;
    long long tile = (long long)((blockIdx.x & 7) * runs + (blockIdx.x >> 3));
    if (tile >= ntiles) return;
    const int tid = (int)threadIdx.x;
    const int wv = tid >> 6;
    const int lane = tid & 63;
    const int m = lane & 15, q = lane >> 4;
    const int qr = (CIN == 32) ? q : (q & 1);
    const long long j0 = tile * 64;

    // R0: init bounds + zero row
    if (tid < 3) { blo[tid] = 0x7fffffff; bhi[tid] = -1; }
    if (tid < CIN / 2) ((unsigned*)(bandmem + ZROW * CIN))[tid] = 0u;
    __syncthreads();

    // R1: band bounds — full min/max over all window entries (8 lanes/window)
    {
        int k = tid >> 3;
        if (k < 27) {
            int s = st[k * (T + 1) + (int)tile];
            int e = st[k * (T + 1) + (int)tile + 1];
            int g = k / 9;
            int lmin = 0x7fffffff, lmax = -1;
            for (int i = s + (tid & 7); i < e; i += 8) {
                int v = km_in[(long long)k * P + i];
                lmin = v < lmin ? v : lmin;
                lmax = v > lmax ? v : lmax;
            }
            if (lmax >= 0) { atomicMin(&blo[g], lmin); atomicMax(&bhi[g], lmax); }
        }
    }
    __syncthreads();

    // R2: per-step fallback flags + band staging (coalesced, XOR-swizzled)
    if (tid < STEPS) {
        int k0 = (CIN == 32) ? tid : 2 * tid;
        int g0 = k0 / 9;
        bool fb = ((long long)bhi[g0] - blo[g0] + 1) > CAP;
        if (CIN == 16) {
            int k1 = 2 * tid + 1;
            if (k1 < 27) {
                int g1 = k1 / 9;
                fb = fb || (((long long)bhi[g1] - blo[g1] + 1) > CAP);
            }
        }
        fbstep[tid] = fb ? 1 : 0;
    }
    for (int g = 0; g < 3; ++g) {
        int lo = blo[g];
        long long w = (long long)bhi[g] - lo + 1;
        if (w <= 0 || w > CAP) continue;
        int qs = tid & (NS16 - 1);
        for (int r = tid / NS16; r < (int)w; r += TPB / NS16) {
            int R = g * CAP + r;
            int slot = qs ^ (R & (NS16 - 1));
            *(short8*)(bandmem + R * CIN + slot * 8) =
                *(const short8*)(xb + (long long)(lo + r) * CIN + qs * 8);
        }
    }
    __syncthreads();

    // R3: lidx prefill with mode-matched pad
    for (int x = tid; x < NK * 64; x += TPB) {
        int k = x >> 6;
        int sidx = (CIN == 32) ? k : (k >> 1);
        lidx[x] = fbstep[sidx] ? n_in : ZROW;
    }
    __syncthreads();

    // R4: window scatter into lidx
    {
        int k = tid >> 3;
        if (k < 27) {
            int s = st[k * (T + 1) + (int)tile];
            int e = st[k * (T + 1) + (int)tile + 1];
            int g = k / 9;
            int sidx = (CIN == 32) ? k : (k >> 1);
            int fb = fbstep[sidx];
            int lo = blo[g];
            for (int i = s + (tid & 7); i < e; i += 8) {
                int o = km_out[(long long)k * P + i];
                int gi = km_in[(long long)k * P + i];
                lidx[k * 64 + (o - (int)j0)] = fb ? gi : (g * CAP + (gi - lo));
            }
        }
    }
    __syncthreads();

    // R5: MFMA from LDS bands (global fallback per step), M-split epilogue
    floatx4 acc[NT];
#pragma unroll
    for (int nt = 0; nt < NT; ++nt) acc[nt] = floatx4{0.f, 0.f, 0.f, 0.f};

    int lv[STEPS];
#pragma unroll
    for (int s = 0; s < STEPS; ++s) {
        const int ks = (CIN == 32) ? s : 2 * s + (q >> 1);
        lv[s] = lidx[ks * 64 + wv * 16 + m];
    }
#pragma unroll
    for (int s = 0; s < STEPS; ++s) {
        short8 a;
        if (fbstep[s]) {
            a = *(const short8*)(xb + (long long)lv[s] * CIN + qr * 8);
        } else {
            int R = lv[s];
            int slot = qr ^ (R & (NS16 - 1));
            a = *(const short8*)(bandmem + R * CIN + slot * 8);
        }
        short8 b0 = *(const short8*)(Wp + (((s * 4 + q) * COUT) + m) * 8);
        acc[0] = __builtin_amdgcn_mfma_f32_16x16x32_bf16(a, b0, acc[0], 0, 0, 0);
        if (NT == 2) {
            short8 b1 = *(const short8*)(Wp + (((s * 4 + q) * COUT) + 16 + m) * 8);
            acc[1] = __builtin_amdgcn_mfma_f32_16x16x32_bf16(a, b1, acc[1], 0, 0, 0);
        }
    }

    float bs[2];
    bs[0] = bias[m];
    if (NT == 2) bs[1] = bias[16 + m];
    long long jb = j0 + wv * 16;             // this wave's 16 output rows
#pragma unroll
    for (int u = 0; u < 4; ++u) {
        long long r = jb + q * 4 + u;        // C/D: row=(lane>>4)*4+reg
        if (r < n_out) {
#pragma unroll
            for (int nt = 0; nt < NT; ++nt) {
                float v = acc[nt][u] + bs[nt];
                if (RES) v += b2f(resb[r * COUT + nt * 16 + m]);
                if (RELU) v = fmaxf(v, 0.f);
                if (WF32) outf[r * COUT + nt * 16 + m] = v;
                if (WB16) outb[r * COUT + nt * 16 + m] = f2b(v);
            }
        }
    }
}

// ---------- down conv: K-split tab path (kmd unsorted) ----------
// CIN=16 -> COUT=32, 4 paired steps; wave wv does step wv over all 4
// subtiles (ILP-4 gathers), partials reduced via LDS.
__global__ __launch_bounds__(TPB, 4) void conv_down_k(
    const unsigned short* __restrict__ xb, const unsigned short* __restrict__ Wp,
    const float* __restrict__ bias,
    const int* __restrict__ tab, long long rowcap, int n_in, int n_out,
    long long ntiles, unsigned short* __restrict__ outb) {
    __shared__ floatx4 red[2][12 * 64];      // 16B lane stride: 2-way = free
    int runs = (int)gridDim.x >> 3;
    long long tile = (long long)((blockIdx.x & 7) * runs + (blockIdx.x >> 3));
    if (tile >= ntiles) return;
    int wv = (int)((threadIdx.x >> 6) & 3);
    int lane = (int)threadIdx.x & 63;
    int m = lane & 15, q = lane >> 4;
    long long j0 = tile * 64;

    floatx4 acc[4][2];
#pragma unroll
    for (int t = 0; t < 4; ++t) { acc[t][0] = floatx4{0,0,0,0}; acc[t][1] = floatx4{0,0,0,0}; }

    const int coff = (q & 1) * 8;
    const int s = wv;                        // one step per wave
    {
        const int ks = 2 * s + (q >> 1);
        const int* trow = tab + (long long)ks * rowcap + j0 + m;
        int idx[4];
#pragma unroll
        for (int t = 0; t < 4; ++t) {
            unsigned v = (unsigned)trow[16 * t];
            idx[t] = (int)(v < (unsigned)n_in ? v : (unsigned)n_in);
        }
        short8 b0 = *(const short8*)(Wp + (((s * 4 + q) * 32) + m) * 8);
        short8 b1 = *(const short8*)(Wp + (((s * 4 + q) * 32) + 16 + m) * 8);
#pragma unroll
        for (int t = 0; t < 4; ++t) {
            short8 a = *(const short8*)(xb + (long long)idx[t] * 16 + coff);
            acc[t][0] = __builtin_amdgcn_mfma_f32_16x16x32_bf16(a, b0, acc[t][0], 0, 0, 0);
            acc[t][1] = __builtin_amdgcn_mfma_f32_16x16x32_bf16(a, b1, acc[t][1], 0, 0, 0);
        }
    }
#pragma unroll
    for (int t = 0; t < 4; ++t) {
        if (t != wv) {
            int sl = wv * 3 + (t > wv ? t - 1 : t);
            red[0][sl * 64 + lane] = acc[t][0];
            red[1][sl * 64 + lane] = acc[t][1];
        }
    }
    floatx4 own[2];
    own[0] = acc[0][0]; own[1] = acc[0][1];
#pragma unroll
    for (int t = 1; t < 4; ++t)
        if (wv == t) { own[0] = acc[t][0]; own[1] = acc[t][1]; }
    __syncthreads();
#pragma unroll
    for (int w = 0; w < 4; ++w) {
        if (w != wv) {
            int sl = w * 3 + (wv > w ? wv - 1 : wv);
            own[0] += red[0][sl * 64 + lane];
            own[1] += red[1][sl * 64 + lane];
        }
    }
    float bs0 = bias[m], bs1 = bias[16 + m];
    long long jb = j0 + wv * 16;
#pragma unroll
    for (int u = 0; u < 4; ++u) {
        long long r = jb + q * 4 + u;
        if (r < n_out) {
            float v0 = fmaxf(own[0][u] + bs0, 0.f);
            float v1 = fmaxf(own[1][u] + bs1, 0.f);
            outb[r * 32 + m] = f2b(v0);
            outb[r * 32 + 16 + m] = f2b(v1);
        }
    }
}

static inline unsigned nblk(long long n, int b) { return (unsigned)((n + b - 1) / b); }
static inline unsigned pad8(unsigned g) { return ((g + 7) / 8) * 8; }
static inline size_t align64(size_t x) { return (x + 63) & ~(size_t)63; }

extern "C" void kernel_launch(void* const* d_in, const int* in_sizes, int n_in_cnt,
                              void* d_out, int out_size, void* d_ws, size_t ws_size,
                              hipStream_t stream) {
    const float* in_feats = (const float*)d_in[0];
    const float* W_first = (const float*)d_in[1];
    const float* b_first = (const float*)d_in[2];
    const float* W_pre   = (const float*)d_in[3];
    const float* b_pre   = (const float*)d_in[4];
    const float* W_down  = (const float*)d_in[5];
    const float* b_down  = (const float*)d_in[6];
    const float* W_r0    = (const float*)d_in[7];
    const float* b_r0    = (const float*)d_in[8];
    const float* W_r1    = (const float*)d_in[9];
    const float* b_r1    = (const float*)d_in[10];
    const float* W_fin   = (const float*)d_in[11];
    const float* b_fin   = (const float*)d_in[12];
    const int* km0_in  = (const int*)d_in[13];
    const int* km0_out = (const int*)d_in[14];
    const int* kmd_in  = (const int*)d_in[15];
    const int* kmd_out = (const int*)d_in[16];
    const int* km1_in  = (const int*)d_in[17];
    const int* km1_out = (const int*)d_in[18];

    const int n0 = in_sizes[0];
    const int n1 = (out_size - 16 * n0) / 32;
    const long long P0 = in_sizes[13] / 27;
    const long long Pd = in_sizes[15] / 8;
    const long long P1 = in_sizes[17] / 27;

    const long long rc1 = ((n1 + 64) / 64) * 64;
    const long long rc0 = ((n0 + 64) / 64) * 64;
    const int T0 = (int)(rc0 / 64), T1 = (int)(rc1 / 64);

    float* out_lo = (float*)d_out;                 // (n1,32)
    float* cached = out_lo + (size_t)n1 * 32;      // (n0,16) f32

    char* base = (char*)d_ws;
    size_t off = 0;
    auto alloc = [&](size_t bytes) { void* p = base + off; off = align64(off + bytes); return p; };
    int* td = (int*)alloc(sizeof(int) * 8 * rc1);      // down tab (kmd unsorted)
    int* st0 = (int*)alloc(sizeof(int) * 27 * (T0 + 1));
    int* st1 = (int*)alloc(sizeof(int) * 27 * (T1 + 1));
    unsigned short* c0b   = (unsigned short*)alloc(sizeof(short) * 16 * (n0 + 1));
    unsigned short* x0pre = (unsigned short*)alloc(sizeof(short) * 16 * (n0 + 1));
    unsigned short* x1a   = (unsigned short*)alloc(sizeof(short) * 32 * (n1 + 1));
    unsigned short* x1b   = (unsigned short*)alloc(sizeof(short) * 32 * (n1 + 1));
    unsigned short* x1c   = (unsigned short*)alloc(sizeof(short) * 32 * (n1 + 1));
    unsigned short* wp_pre  = (unsigned short*)alloc(sizeof(short) * 14 * 4 * 16 * 8);
    unsigned short* wp_down = (unsigned short*)alloc(sizeof(short) * 4 * 4 * 32 * 8);
    unsigned short* wp_r0   = (unsigned short*)alloc(sizeof(short) * 27 * 1024);
    unsigned short* wp_r1   = (unsigned short*)alloc(sizeof(short) * 27 * 1024);
    unsigned short* wp_fin  = (unsigned short*)alloc(sizeof(short) * 27 * 1024);
    (void)ws_size; (void)n_in_cnt;

    // CSR window tables
    const long long searchN = 27LL * (T0 + 1) + 27LL * (T1 + 1);
    search_k<<<nblk(searchN, TPB), TPB, 0, stream>>>(
        km0_out, km1_out, P0, P1, T0, T1, n0, n1, st0, st1);

    // td scatter + weight packing + pad-row zeroing (td: NO fill — poison
    // slots >= n_in clamp to the zero row in conv_down_k)
    const long long prepN = 8 * Pd + 7168 + 4096 + 3 * 27648 + 128;
    prep_all<<<nblk(prepN, TPB), TPB, 0, stream>>>(
        kmd_in, kmd_out, td, (unsigned)Pd, (unsigned)rc1, (unsigned)n1,
        W_pre, W_down, W_r0, W_r1, W_fin,
        wp_pre, wp_down, wp_r0, wp_r1, wp_fin,
        c0b + (size_t)n0 * 16, x0pre + (size_t)n0 * 16,
        x1a + (size_t)n1 * 32, x1b + (size_t)n1 * 32, x1c + (size_t)n1 * 32);

    // first: 1 -> 16, relu -> cached (f32) + c0b (bf16)
    conv_first_k<<<nblk(n0, TPB), TPB, 0, stream>>>(
        in_feats, W_first, b_first, km0_in, km0_out, st0, P0, T0, n0, cached, c0b);

    const unsigned g0 = pad8((unsigned)T0), g1 = pad8((unsigned)T1);
    // pre: 16 -> 16 relu; 14 paired steps cover 27 offsets (+pad row 27)
    conv_band<16, 16, 14, true, false, false, true><<<g0, TPB, 0, stream>>>(
        c0b, wp_pre, b_pre, km0_in, km0_out, st0, T0, P0,
        n0, n0, T0, nullptr, nullptr, x0pre);
    // down: 16 -> 32 relu; tab path
    conv_down_k<<<g1, TPB, 0, stream>>>(
        x0pre, wp_down, b_down, td, rc1, n0, n1, T1, x1a);
    // r0: 32 -> 32 relu
    conv_band<32, 32, 27, true, false, false, true><<<g1, TPB, 0, stream>>>(
        x1a, wp_r0, b_r0, km1_in, km1_out, st1, T1, P1,
        n1, n1, T1, nullptr, nullptr, x1b);
    // r1: 32 -> 32 + residual x1a, no relu
    conv_band<32, 32, 27, false, true, false, true><<<g1, TPB, 0, stream>>>(
        x1b, wp_r1, b_r1, km1_in, km1_out, st1, T1, P1,
        n1, n1, T1, x1a, nullptr, x1c);
    // fin: 32 -> 32 -> d_out (f32)
    conv_band<32, 32, 27, false, false, true, false><<<g1, TPB, 0, stream>>>(
        x1c, wp_fin, b_fin, km1_in, km1_out, st1, T1, P1,
        n1, n1, T1, nullptr, out_lo, nullptr);
}

// Round 11
// 567.385 us; speedup vs baseline: 1.0333x; 1.0333x over previous
//
#include <hip/hip_runtime.h>

// Sparse-conv encoder, bf16-MFMA implicit-GEMM.
// Round-20 change: band staging v2. Round-19's idea was right (the 32-ch
// convs are L1/TA-bound on 64-lane divergent gathers, schedule-invariant
// 55-63us; FETCH unchanged proves it never was HBM) but execution lost to
// (a) 8-way correlated LDS bank conflicts (64B row stride: bank group =
// R&1 only; 3.95M conflicts), (b) O(window) min/max scans+atomics, (c) 5
// barriers. v2: bounds from FIRST/LAST window entry (km_in windows are
// sorted: fixed offset preserves lex order), padded row stride CIN+8 halfs
// (16B-aligned rows, bank base cycles 8 groups with R mod 8), all band
// state in scalars (rule-#20), 4 barriers, CAP=128 (bands ~70 wide:
// in = out + plane-shift +- few, contiguous across plane boundaries).
// Per-step global fallback kept for correctness on wide bands.

#define TPB 256

typedef __attribute__((ext_vector_type(8))) short short8;
typedef __attribute__((ext_vector_type(4))) float floatx4;

static __device__ __forceinline__ unsigned short f2b(float f) {
    union { float f; unsigned u; } v; v.f = f;
    unsigned r = v.u + 0x7fffu + ((v.u >> 16) & 1u);   // RNE
    return (unsigned short)(r >> 16);
}
static __device__ __forceinline__ float b2f(unsigned short h) {
    union { unsigned u; float f; } v; v.u = ((unsigned)h) << 16;
    return v.f;
}

// ---------- CSR window boundaries ----------
// st[k][tile] = lower_bound(km_out[k], min(tile*64, n)), tile in [0, T].
__global__ void search_k(const int* __restrict__ km0_out,
                         const int* __restrict__ km1_out,
                         long long P0, long long P1, int T0, int T1,
                         int n0, int n1,
                         int* __restrict__ st0, int* __restrict__ st1) {
    unsigned t = blockIdx.x * blockDim.x + threadIdx.x;
    unsigned N0 = 27u * (unsigned)(T0 + 1);
    unsigned N1 = 27u * (unsigned)(T1 + 1);
    const int* row;
    long long P;
    int th;
    int* dst;
    if (t < N0) {
        unsigned k = t / (unsigned)(T0 + 1), tile = t - k * (unsigned)(T0 + 1);
        row = km0_out + (long long)k * P0; P = P0;
        long long thr = (long long)tile * 64;
        th = thr < n0 ? (int)thr : n0;
        dst = st0 + t;
    } else {
        t -= N0;
        if (t >= N1) return;
        unsigned k = t / (unsigned)(T1 + 1), tile = t - k * (unsigned)(T1 + 1);
        row = km1_out + (long long)k * P1; P = P1;
        long long thr = (long long)tile * 64;
        th = thr < n1 ? (int)thr : n1;
        dst = st1 + t;
    }
    long long lo = 0, hi = P;
    while (lo < hi) {
        long long mid = (lo + hi) >> 1;
        if (row[mid] < th) lo = mid + 1; else hi = mid;
    }
    *dst = (int)lo;
}

static __device__ __forceinline__ void pack16_elem(
    const float* __restrict__ W, unsigned short* __restrict__ Wp,
    int t, int COUT, int Ksrc) {
    int j = t & 7;
    int r = t >> 3;
    int n = r % COUT; r /= COUT;
    int q = r & 3;
    int k2 = r >> 2;
    int ks = 2 * k2 + (q >> 1);
    int cin = (q & 1) * 8 + j;
    float v = (ks < Ksrc) ? W[(ks * 16 + cin) * COUT + n] : 0.f;
    Wp[t] = f2b(v);
}

// one dispatch: td scatter (kmd unsorted -> tab path) + all weight packing
// + zero pad rows of the 5 bf16 feature buffers
__global__ void prep_all(const int* __restrict__ kmd_in, const int* __restrict__ kmd_out,
                         int* __restrict__ td, unsigned Pd, unsigned rc1, unsigned n1,
                         const float* __restrict__ W_pre, const float* __restrict__ W_down,
                         const float* __restrict__ W_r0, const float* __restrict__ W_r1,
                         const float* __restrict__ W_fin,
                         unsigned short* __restrict__ wp_pre, unsigned short* __restrict__ wp_down,
                         unsigned short* __restrict__ wp_r0, unsigned short* __restrict__ wp_r1,
                         unsigned short* __restrict__ wp_fin,
                         unsigned short* p0, unsigned short* p1, unsigned short* p2,
                         unsigned short* p3, unsigned short* p4) {
    unsigned tu = blockIdx.x * blockDim.x + threadIdx.x;
    unsigned Nd = 8u * Pd;
    if (tu < Nd) {                    // td scatter: 1 entry/thread, guarded store
        int o = kmd_out[tu];
        int i = kmd_in[tu];
        if ((unsigned)o < n1) td[(tu / Pd) * rc1 + (unsigned)o] = i;
        return;
    }
    int t = (int)(tu - Nd);
    if (t < 7168) { pack16_elem(W_pre, wp_pre, t, 16, 27); return; }
    t -= 7168;
    if (t < 4096) { pack16_elem(W_down, wp_down, t, 32, 8); return; }
    t -= 4096;
    if (t < 27648) {   // W (27,32,32): Wp[((k*4+q)*32+n)*8+j] = W[k][q*8+j][n]
        int j = t & 7, n = (t >> 3) & 31, q = (t >> 8) & 3, k = t >> 10;
        wp_r0[t] = f2b(W_r0[(k * 32 + q * 8 + j) * 32 + n]); return;
    }
    t -= 27648;
    if (t < 27648) {
        int j = t & 7, n = (t >> 3) & 31, q = (t >> 8) & 3, k = t >> 10;
        wp_r1[t] = f2b(W_r1[(k * 32 + q * 8 + j) * 32 + n]); return;
    }
    t -= 27648;
    if (t < 27648) {
        int j = t & 7, n = (t >> 3) & 31, q = (t >> 8) & 3, k = t >> 10;
        wp_fin[t] = f2b(W_fin[(k * 32 + q * 8 + j) * 32 + n]); return;
    }
    t -= 27648;
    if (t < 16) p0[t] = 0;
    else if (t < 32) p1[t - 16] = 0;
    else if (t < 64) p2[t - 32] = 0;
    else if (t < 96) p3[t - 64] = 0;
    else if (t < 128) p4[t - 96] = 0;
}

// first conv: C_IN=1 -> 16, K=27, relu; CSR idx build into LDS (256 rows/
// block). Writes f32 (cached out) + bf16 copy.
__global__ __launch_bounds__(TPB) void conv_first_k(
    const float* __restrict__ xin, const float* __restrict__ W,
    const float* __restrict__ b,
    const int* __restrict__ km_in, const int* __restrict__ km_out,
    const int* __restrict__ st, long long P, int T,
    int n0, float* __restrict__ outf, unsigned short* __restrict__ outb) {
    __shared__ int lidx[27][256];
    const int blk = (int)blockIdx.x;
    const int j0 = blk * 256;
    const int wv = (int)(threadIdx.x >> 6), lane = (int)(threadIdx.x & 63);
    const int ta = 4 * blk;
    const int tb = (4 * blk + 4 < T) ? 4 * blk + 4 : T;
    for (int r = wv; r < 27; r += 4) {
#pragma unroll
        for (int i = 0; i < 4; ++i) lidx[r][lane + 64 * i] = n0;   // pad
        int s = st[r * (T + 1) + ta];
        int e = st[r * (T + 1) + tb];
        for (int i = s + lane; i < e; i += 64) {
            int o = km_out[(long long)r * P + i];
            lidx[r][o - j0] = km_in[(long long)r * P + i];
        }
    }
    __syncthreads();
    int j = j0 + (int)threadIdx.x;
    if (j >= n0) return;
    float acc[16];
#pragma unroll
    for (int c = 0; c < 16; ++c) acc[c] = b[c];
#pragma unroll
    for (int k = 0; k < 27; ++k) {
        int idx = lidx[k][threadIdx.x];
        bool ok = idx < n0;
        int cidx = ok ? idx : 0;
        float v = xin[cidx];
        v = ok ? v : 0.f;
        const float* Wk = W + k * 16;
#pragma unroll
        for (int c = 0; c < 16; ++c) acc[c] = fmaf(v, Wk[c], acc[c]);
    }
    float* orow = outf + (long long)j * 16;
    unsigned short* brow = outb + (long long)j * 16;
#pragma unroll
    for (int c = 0; c < 16; ++c) {
        float v = fmaxf(acc[c], 0.f);
        orow[c] = v;
        brow[c] = f2b(v);
    }
}

// ---------- LDS-band conv v2 (CSR, sorted km rows) ----------
// Block = one 64-row tile, M-split (wave wv owns subtile wv). Bands g=k/9
// staged into LDS with padded row stride RST=CIN+8 halfs (16B-aligned rows,
// bank base cycles 8 groups with R mod 8). Bounds = first/last window entry
// (km_in windows sorted). Bands wider than CAP fall back per-step to global
// gather. All band state in scalars (no runtime-indexed register arrays).
template <int CIN, int COUT, int STEPS, bool RELU, bool RES, bool WF32, bool WB16>
__global__ __launch_bounds__(TPB, 4) void conv_band(
    const unsigned short* __restrict__ xb,   // (n_in+1, CIN) bf16, pad row zero
    const unsigned short* __restrict__ Wp,
    const float* __restrict__ bias,
    const int* __restrict__ km_in, const int* __restrict__ km_out,
    const int* __restrict__ st, int T, long long P,
    int n_in, int n_out, long long ntiles,
    const unsigned short* __restrict__ resb,
    float* __restrict__ outf, unsigned short* __restrict__ outb) {
    constexpr int NT = COUT / 16;
    constexpr int NK = (CIN == 16) ? 2 * STEPS : STEPS;  // lidx rows (28/27)
    constexpr int RST = CIN + 8;             // padded LDS row stride (halfs)
    constexpr int NS16 = (CIN * 2) / 16;     // 16B slots per row: 4 / 2
    constexpr int CAP = 128;
    constexpr int ZROW = 3 * CAP;            // zeroed pad row
    __shared__ unsigned short bandmem[(3 * CAP + 1) * RST];
    __shared__ int lidx[NK * 64];
    __shared__ int sbnd[6];                  // lo[3], hi[3]

    // bijective XCD swizzle: gridDim.x % 8 == 0
    int runs = (int)gridDim.x >> 3;
    long long tile = (long long)((blockIdx.x & 7) * runs + (blockIdx.x >> 3));
    if (tile >= ntiles) return;              // uniform across block
    const int tid = (int)threadIdx.x;
    const int wv = tid >> 6;
    const int lane = tid & 63;
    const int m = lane & 15, q = lane >> 4;
    const int qr = (CIN == 32) ? q : (q & 1);
    const long long j0 = tile * 64;

    // P0: init bounds + zero pad row
    if (tid < 3) { sbnd[tid] = 0x7fffffff; sbnd[3 + tid] = -1; }
    if (tid >= 64 && tid < 64 + RST) bandmem[ZROW * RST + (tid - 64)] = 0;
    __syncthreads();

    // P1: band bounds = first/last entry of each window (windows sorted)
    if (tid < 27) {
        int s = st[tid * (T + 1) + (int)tile];
        int e = st[tid * (T + 1) + (int)tile + 1];
        if (e > s) {
            int g = (tid >= 18) ? 2 : (tid >= 9 ? 1 : 0);
            atomicMin(&sbnd[g], km_in[(long long)tid * P + s]);
            atomicMax(&sbnd[3 + g], km_in[(long long)tid * P + e - 1]);
        }
    }
    __syncthreads();

    // band state in scalars (rule-#20: no runtime-indexed register arrays)
    const int lo0 = sbnd[0], lo1 = sbnd[1], lo2 = sbnd[2];
    long long w0l = (long long)sbnd[3] - lo0 + 1;
    long long w1l = (long long)sbnd[4] - lo1 + 1;
    long long w2l = (long long)sbnd[5] - lo2 + 1;
    const int wd0 = w0l > 0 ? (int)w0l : 0;
    const int wd1 = w1l > 0 ? (int)w1l : 0;
    const int wd2 = w2l > 0 ? (int)w2l : 0;
    const bool ok0 = wd0 <= CAP, ok1 = wd1 <= CAP, ok2 = wd2 <= CAP;
    auto bandok = [&](int k) -> bool { return k >= 18 ? ok2 : (k >= 9 ? ok1 : ok0); };
    auto stepfb = [&](int s) -> bool {       // block-uniform per-step fallback
        if (CIN == 32) return !bandok(s);
        bool f = !bandok(2 * s);
        if (2 * s + 1 < 27) f = f || !bandok(2 * s + 1);
        return f;
    };

    // P2a: stage bands coalesced into padded LDS rows
    {
        const int qs = tid & (NS16 - 1);
        const int r0 = tid / NS16;
        if (ok0) for (int r = r0; r < wd0; r += TPB / NS16)
            *(short8*)(bandmem + (0 * CAP + r) * RST + qs * 8) =
                *(const short8*)(xb + (long long)(lo0 + r) * CIN + qs * 8);
        if (ok1) for (int r = r0; r < wd1; r += TPB / NS16)
            *(short8*)(bandmem + (1 * CAP + r) * RST + qs * 8) =
                *(const short8*)(xb + (long long)(lo1 + r) * CIN + qs * 8);
        if (ok2) for (int r = r0; r < wd2; r += TPB / NS16)
            *(short8*)(bandmem + (2 * CAP + r) * RST + qs * 8) =
                *(const short8*)(xb + (long long)(lo2 + r) * CIN + qs * 8);
    }
    // P2b: lidx prefill, pad value matches the step's mode
    for (int x = tid; x < NK * 64; x += TPB) {
        int k = x >> 6;
        int sidx = (CIN == 32) ? k : (k >> 1);
        lidx[x] = stepfb(sidx) ? n_in : ZROW;
    }
    __syncthreads();

    // P3: window scatter into lidx (8 lanes per k-window; windows <= 64)
    {
        int k = tid >> 3;
        if (k < 27) {
            int s = st[k * (T + 1) + (int)tile];
            int e = st[k * (T + 1) + (int)tile + 1];
            int g = (k >= 18) ? 2 : (k >= 9 ? 1 : 0);
            bool fb = !(g == 0 ? ok0 : (g == 1 ? ok1 : ok2));
            int lg = (g == 0) ? lo0 : (g == 1 ? lo1 : lo2);
            int gb = g * CAP;
            for (int i = s + (tid & 7); i < e; i += 8) {
                int o = km_out[(long long)k * P + i];
                int gi = km_in[(long long)k * P + i];
                lidx[k * 64 + (o - (int)j0)] = fb ? gi : (gb + (gi - lg));
            }
        }
    }
    __syncthreads();

    // P4: MFMA from LDS bands (global fallback per step), M-split epilogue
    floatx4 acc[NT];
#pragma unroll
    for (int nt = 0; nt < NT; ++nt) acc[nt] = floatx4{0.f, 0.f, 0.f, 0.f};

    int lv[STEPS];
#pragma unroll
    for (int s = 0; s < STEPS; ++s) {
        const int ks = (CIN == 32) ? s : 2 * s + (q >> 1);
        lv[s] = lidx[ks * 64 + wv * 16 + m];
    }
#pragma unroll
    for (int s = 0; s < STEPS; ++s) {
        short8 a;
        if (stepfb(s)) {
            a = *(const short8*)(xb + (long long)lv[s] * CIN + qr * 8);
        } else {
            a = *(const short8*)(bandmem + lv[s] * RST + qr * 8);
        }
        short8 b0 = *(const short8*)(Wp + (((s * 4 + q) * COUT) + m) * 8);
        acc[0] = __builtin_amdgcn_mfma_f32_16x16x32_bf16(a, b0, acc[0], 0, 0, 0);
        if (NT == 2) {
            short8 b1 = *(const short8*)(Wp + (((s * 4 + q) * COUT) + 16 + m) * 8);
            acc[1] = __builtin_amdgcn_mfma_f32_16x16x32_bf16(a, b1, acc[1], 0, 0, 0);
        }
    }

    float bs[2];
    bs[0] = bias[m];
    if (NT == 2) bs[1] = bias[16 + m];
    long long jb = j0 + wv * 16;             // this wave's 16 output rows
#pragma unroll
    for (int u = 0; u < 4; ++u) {
        long long r = jb + q * 4 + u;        // C/D: row=(lane>>4)*4+reg
        if (r < n_out) {
#pragma unroll
            for (int nt = 0; nt < NT; ++nt) {
                float v = acc[nt][u] + bs[nt];
                if (RES) v += b2f(resb[r * COUT + nt * 16 + m]);
                if (RELU) v = fmaxf(v, 0.f);
                if (WF32) outf[r * COUT + nt * 16 + m] = v;
                if (WB16) outb[r * COUT + nt * 16 + m] = f2b(v);
            }
        }
    }
}

// ---------- down conv: K-split tab path (kmd unsorted) ----------
// CIN=16 -> COUT=32, 4 paired steps; wave wv does step wv over all 4
// subtiles (ILP-4 gathers), partials reduced via LDS.
__global__ __launch_bounds__(TPB, 4) void conv_down_k(
    const unsigned short* __restrict__ xb, const unsigned short* __restrict__ Wp,
    const float* __restrict__ bias,
    const int* __restrict__ tab, long long rowcap, int n_in, int n_out,
    long long ntiles, unsigned short* __restrict__ outb) {
    __shared__ floatx4 red[2][12 * 64];      // 16B lane stride: 2-way = free
    int runs = (int)gridDim.x >> 3;
    long long tile = (long long)((blockIdx.x & 7) * runs + (blockIdx.x >> 3));
    if (tile >= ntiles) return;
    int wv = (int)((threadIdx.x >> 6) & 3);
    int lane = (int)threadIdx.x & 63;
    int m = lane & 15, q = lane >> 4;
    long long j0 = tile * 64;

    floatx4 acc[4][2];
#pragma unroll
    for (int t = 0; t < 4; ++t) { acc[t][0] = floatx4{0,0,0,0}; acc[t][1] = floatx4{0,0,0,0}; }

    const int coff = (q & 1) * 8;
    const int s = wv;                        // one step per wave
    {
        const int ks = 2 * s + (q >> 1);
        const int* trow = tab + (long long)ks * rowcap + j0 + m;
        int idx[4];
#pragma unroll
        for (int t = 0; t < 4; ++t) {
            unsigned v = (unsigned)trow[16 * t];
            idx[t] = (int)(v < (unsigned)n_in ? v : (unsigned)n_in);
        }
        short8 b0 = *(const short8*)(Wp + (((s * 4 + q) * 32) + m) * 8);
        short8 b1 = *(const short8*)(Wp + (((s * 4 + q) * 32) + 16 + m) * 8);
#pragma unroll
        for (int t = 0; t < 4; ++t) {
            short8 a = *(const short8*)(xb + (long long)idx[t] * 16 + coff);
            acc[t][0] = __builtin_amdgcn_mfma_f32_16x16x32_bf16(a, b0, acc[t][0], 0, 0, 0);
            acc[t][1] = __builtin_amdgcn_mfma_f32_16x16x32_bf16(a, b1, acc[t][1], 0, 0, 0);
        }
    }
#pragma unroll
    for (int t = 0; t < 4; ++t) {
        if (t != wv) {
            int sl = wv * 3 + (t > wv ? t - 1 : t);
            red[0][sl * 64 + lane] = acc[t][0];
            red[1][sl * 64 + lane] = acc[t][1];
        }
    }
    floatx4 own[2];
    own[0] = acc[0][0]; own[1] = acc[0][1];
#pragma unroll
    for (int t = 1; t < 4; ++t)
        if (wv == t) { own[0] = acc[t][0]; own[1] = acc[t][1]; }
    __syncthreads();
#pragma unroll
    for (int w = 0; w < 4; ++w) {
        if (w != wv) {
            int sl = w * 3 + (wv > w ? wv - 1 : wv);
            own[0] += red[0][sl * 64 + lane];
            own[1] += red[1][sl * 64 + lane];
        }
    }
    float bs0 = bias[m], bs1 = bias[16 + m];
    long long jb = j0 + wv * 16;
#pragma unroll
    for (int u = 0; u < 4; ++u) {
        long long r = jb + q * 4 + u;
        if (r < n_out) {
            float v0 = fmaxf(own[0][u] + bs0, 0.f);
            float v1 = fmaxf(own[1][u] + bs1, 0.f);
            outb[r * 32 + m] = f2b(v0);
            outb[r * 32 + 16 + m] = f2b(v1);
        }
    }
}

static inline unsigned nblk(long long n, int b) { return (unsigned)((n + b - 1) / b); }
static inline unsigned pad8(unsigned g) { return ((g + 7) / 8) * 8; }
static inline size_t align64(size_t x) { return (x + 63) & ~(size_t)63; }

extern "C" void kernel_launch(void* const* d_in, const int* in_sizes, int n_in_cnt,
                              void* d_out, int out_size, void* d_ws, size_t ws_size,
                              hipStream_t stream) {
    const float* in_feats = (const float*)d_in[0];
    const float* W_first = (const float*)d_in[1];
    const float* b_first = (const float*)d_in[2];
    const float* W_pre   = (const float*)d_in[3];
    const float* b_pre   = (const float*)d_in[4];
    const float* W_down  = (const float*)d_in[5];
    const float* b_down  = (const float*)d_in[6];
    const float* W_r0    = (const float*)d_in[7];
    const float* b_r0    = (const float*)d_in[8];
    const float* W_r1    = (const float*)d_in[9];
    const float* b_r1    = (const float*)d_in[10];
    const float* W_fin   = (const float*)d_in[11];
    const float* b_fin   = (const float*)d_in[12];
    const int* km0_in  = (const int*)d_in[13];
    const int* km0_out = (const int*)d_in[14];
    const int* kmd_in  = (const int*)d_in[15];
    const int* kmd_out = (const int*)d_in[16];
    const int* km1_in  = (const int*)d_in[17];
    const int* km1_out = (const int*)d_in[18];

    const int n0 = in_sizes[0];
    const int n1 = (out_size - 16 * n0) / 32;
    const long long P0 = in_sizes[13] / 27;
    const long long Pd = in_sizes[15] / 8;
    const long long P1 = in_sizes[17] / 27;

    const long long rc1 = ((n1 + 64) / 64) * 64;
    const long long rc0 = ((n0 + 64) / 64) * 64;
    const int T0 = (int)(rc0 / 64), T1 = (int)(rc1 / 64);

    float* out_lo = (float*)d_out;                 // (n1,32)
    float* cached = out_lo + (size_t)n1 * 32;      // (n0,16) f32

    char* base = (char*)d_ws;
    size_t off = 0;
    auto alloc = [&](size_t bytes) { void* p = base + off; off = align64(off + bytes); return p; };
    int* td = (int*)alloc(sizeof(int) * 8 * rc1);      // down tab (kmd unsorted)
    int* st0 = (int*)alloc(sizeof(int) * 27 * (T0 + 1));
    int* st1 = (int*)alloc(sizeof(int) * 27 * (T1 + 1));
    unsigned short* c0b   = (unsigned short*)alloc(sizeof(short) * 16 * (n0 + 1));
    unsigned short* x0pre = (unsigned short*)alloc(sizeof(short) * 16 * (n0 + 1));
    unsigned short* x1a   = (unsigned short*)alloc(sizeof(short) * 32 * (n1 + 1));
    unsigned short* x1b   = (unsigned short*)alloc(sizeof(short) * 32 * (n1 + 1));
    unsigned short* x1c   = (unsigned short*)alloc(sizeof(short) * 32 * (n1 + 1));
    unsigned short* wp_pre  = (unsigned short*)alloc(sizeof(short) * 14 * 4 * 16 * 8);
    unsigned short* wp_down = (unsigned short*)alloc(sizeof(short) * 4 * 4 * 32 * 8);
    unsigned short* wp_r0   = (unsigned short*)alloc(sizeof(short) * 27 * 1024);
    unsigned short* wp_r1   = (unsigned short*)alloc(sizeof(short) * 27 * 1024);
    unsigned short* wp_fin  = (unsigned short*)alloc(sizeof(short) * 27 * 1024);
    (void)ws_size; (void)n_in_cnt;

    // CSR window tables
    const long long searchN = 27LL * (T0 + 1) + 27LL * (T1 + 1);
    search_k<<<nblk(searchN, TPB), TPB, 0, stream>>>(
        km0_out, km1_out, P0, P1, T0, T1, n0, n1, st0, st1);

    // td scatter + weight packing + pad-row zeroing (td: NO fill — poison
    // slots >= n_in clamp to the zero row in conv_down_k)
    const long long prepN = 8 * Pd + 7168 + 4096 + 3 * 27648 + 128;
    prep_all<<<nblk(prepN, TPB), TPB, 0, stream>>>(
        kmd_in, kmd_out, td, (unsigned)Pd, (unsigned)rc1, (unsigned)n1,
        W_pre, W_down, W_r0, W_r1, W_fin,
        wp_pre, wp_down, wp_r0, wp_r1, wp_fin,
        c0b + (size_t)n0 * 16, x0pre + (size_t)n0 * 16,
        x1a + (size_t)n1 * 32, x1b + (size_t)n1 * 32, x1c + (size_t)n1 * 32);

    // first: 1 -> 16, relu -> cached (f32) + c0b (bf16)
    conv_first_k<<<nblk(n0, TPB), TPB, 0, stream>>>(
        in_feats, W_first, b_first, km0_in, km0_out, st0, P0, T0, n0, cached, c0b);

    const unsigned g0 = pad8((unsigned)T0), g1 = pad8((unsigned)T1);
    // pre: 16 -> 16 relu; 14 paired steps cover 27 offsets (+pad row 27)
    conv_band<16, 16, 14, true, false, false, true><<<g0, TPB, 0, stream>>>(
        c0b, wp_pre, b_pre, km0_in, km0_out, st0, T0, P0,
        n0, n0, T0, nullptr, nullptr, x0pre);
    // down: 16 -> 32 relu; tab path
    conv_down_k<<<g1, TPB, 0, stream>>>(
        x0pre, wp_down, b_down, td, rc1, n0, n1, T1, x1a);
    // r0: 32 -> 32 relu
    conv_band<32, 32, 27, true, false, false, true><<<g1, TPB, 0, stream>>>(
        x1a, wp_r0, b_r0, km1_in, km1_out, st1, T1, P1,
        n1, n1, T1, nullptr, nullptr, x1b);
    // r1: 32 -> 32 + residual x1a, no relu
    conv_band<32, 32, 27, false, true, false, true><<<g1, TPB, 0, stream>>>(
        x1b, wp_r1, b_r1, km1_in, km1_out, st1, T1, P1,
        n1, n1, T1, x1a, nullptr, x1c);
    // fin: 32 -> 32 -> d_out (f32)
    conv_band<32, 32, 27, false, false, true, false><<<g1, TPB, 0, stream>>>(
        x1c, wp_fin, b_fin, km1_in, km1_out, st1, T1, P1,
        n1, n1, T1, nullptr, out_lo, nullptr);
}

// Round 12
// 512.207 us; speedup vs baseline: 1.1446x; 1.1077x over previous
//
#include <hip/hip_runtime.h>

// Sparse-conv encoder, bf16-MFMA implicit-GEMM.
// Round-21: REVERT convs to round-8 (best measured: 57us each; rounds 9-11's
// CSR/LDS-band variants all slower) + replace scatter_rows (57us, 55%-dense
// partial-line stores -> RFO traffic, 1.6TB/s) with tabgen: one wave per
// (k,tile) CSR window loads <=64 entries coalesced, scatters into LDS slots
// pre-filled with pad n, block stores 256 consecutive slots -> FULL-LINE
// write streams, no RFO. Write volume 58->96MB but at streaming rate.
// kmd is unsorted -> td scatter stays in prep_all (small).

#define TPB 256

typedef __attribute__((ext_vector_type(8))) short short8;
typedef __attribute__((ext_vector_type(4))) float floatx4;

static __device__ __forceinline__ unsigned short f2b(float f) {
    union { float f; unsigned u; } v; v.f = f;
    unsigned r = v.u + 0x7fffu + ((v.u >> 16) & 1u);   // RNE
    return (unsigned short)(r >> 16);
}
static __device__ __forceinline__ float b2f(unsigned short h) {
    union { unsigned u; float f; } v; v.u = ((unsigned)h) << 16;
    return v.f;
}

// ---------- CSR window boundaries ----------
// st[k][tile] = lower_bound(km_out[k], min(tile*64, n)), tile in [0, T].
__global__ void search_k(const int* __restrict__ km0_out,
                         const int* __restrict__ km1_out,
                         long long P0, long long P1, int T0, int T1,
                         int n0, int n1,
                         int* __restrict__ st0, int* __restrict__ st1) {
    unsigned t = blockIdx.x * blockDim.x + threadIdx.x;
    unsigned N0 = 27u * (unsigned)(T0 + 1);
    unsigned N1 = 27u * (unsigned)(T1 + 1);
    const int* row;
    long long P;
    int th;
    int* dst;
    if (t < N0) {
        unsigned k = t / (unsigned)(T0 + 1), tile = t - k * (unsigned)(T0 + 1);
        row = km0_out + (long long)k * P0; P = P0;
        long long thr = (long long)tile * 64;
        th = thr < n0 ? (int)thr : n0;
        dst = st0 + t;
    } else {
        t -= N0;
        if (t >= N1) return;
        unsigned k = t / (unsigned)(T1 + 1), tile = t - k * (unsigned)(T1 + 1);
        row = km1_out + (long long)k * P1; P = P1;
        long long thr = (long long)tile * 64;
        th = thr < n1 ? (int)thr : n1;
        dst = st1 + t;
    }
    long long lo = 0, hi = P;
    while (lo < hi) {
        long long mid = (lo + hi) >> 1;
        if (row[mid] < th) lo = mid + 1; else hi = mid;
    }
    *dst = (int)lo;
}

// ---------- dense tab build from CSR windows ----------
// blockIdx.y = km row (0..26 -> t0, 27..53 -> t1); blockIdx.x = 4-tile chunk.
// Wave wv handles tile chunk*4+wv: loads its <=64-entry window coalesced,
// scatters into LDS (pad-prefilled with n), then the block stores 256
// consecutive tab slots (1KB full-line stream). Unwritten rows of t0
// (row 27, CIN16 tail) stay harness-poison -> conv clamps.
__global__ __launch_bounds__(TPB) void tabgen(
    const int* __restrict__ km0_in, const int* __restrict__ km0_out,
    const int* __restrict__ km1_in, const int* __restrict__ km1_out,
    const int* __restrict__ st0, const int* __restrict__ st1,
    int* __restrict__ t0, int* __restrict__ t1,
    long long P0, long long P1, int T0, int T1, int n0, int n1) {
    __shared__ int slots[TPB];
    const int w = (int)blockIdx.y;                      // uniform row id
    const int* kin; const int* kout; const int* st; int* tab;
    long long P; int T, n, k;
    if (w < 27) { k = w;      kin = km0_in; kout = km0_out; st = st0; tab = t0; P = P0; T = T0; n = n0; }
    else        { k = w - 27; kin = km1_in; kout = km1_out; st = st1; tab = t1; P = P1; T = T1; n = n1; }
    const int tile0 = (int)blockIdx.x * 4;
    if (tile0 >= T) return;                             // uniform exit
    const int tid = (int)threadIdx.x;
    const int wv = tid >> 6, lane = tid & 63;
    slots[tid] = n;                                     // pad prefill
    __syncthreads();
    const int tile = tile0 + wv;
    if (tile < T) {
        int s = st[k * (T + 1) + tile];
        int e = st[k * (T + 1) + tile + 1];
        if (s + lane < e) {                             // window <= 64 entries
            int o = kout[(long long)k * P + s + lane];
            int i = kin[(long long)k * P + s + lane];
            slots[wv * 64 + (o - tile * 64)] = i;
        }
    }
    __syncthreads();
    const long long rc = (long long)T * 64;
    long long slot = (long long)tile0 * 64 + tid;
    if (slot < rc) tab[(long long)k * rc + slot] = slots[tid];
}

static __device__ __forceinline__ void pack16_elem(
    const float* __restrict__ W, unsigned short* __restrict__ Wp,
    int t, int COUT, int Ksrc) {
    int j = t & 7;
    int r = t >> 3;
    int n = r % COUT; r /= COUT;
    int q = r & 3;
    int k2 = r >> 2;
    int ks = 2 * k2 + (q >> 1);
    int cin = (q & 1) * 8 + j;
    float v = (ks < Ksrc) ? W[(ks * 16 + cin) * COUT + n] : 0.f;
    Wp[t] = f2b(v);
}

// one dispatch: td scatter (kmd unsorted -> tab path) + all weight packing
// + zero pad rows of the 5 bf16 feature buffers
__global__ void prep_all(const int* __restrict__ kmd_in, const int* __restrict__ kmd_out,
                         int* __restrict__ td, unsigned Pd, unsigned rc1, unsigned n1,
                         const float* __restrict__ W_pre, const float* __restrict__ W_down,
                         const float* __restrict__ W_r0, const float* __restrict__ W_r1,
                         const float* __restrict__ W_fin,
                         unsigned short* __restrict__ wp_pre, unsigned short* __restrict__ wp_down,
                         unsigned short* __restrict__ wp_r0, unsigned short* __restrict__ wp_r1,
                         unsigned short* __restrict__ wp_fin,
                         unsigned short* p0, unsigned short* p1, unsigned short* p2,
                         unsigned short* p3, unsigned short* p4) {
    unsigned tu = blockIdx.x * blockDim.x + threadIdx.x;
    unsigned Nd = 8u * Pd;
    if (tu < Nd) {                    // td scatter: 1 entry/thread, guarded store
        int o = kmd_out[tu];
        int i = kmd_in[tu];
        if ((unsigned)o < n1) td[(tu / Pd) * rc1 + (unsigned)o] = i;
        return;
    }
    int t = (int)(tu - Nd);
    if (t < 7168) { pack16_elem(W_pre, wp_pre, t, 16, 27); return; }
    t -= 7168;
    if (t < 4096) { pack16_elem(W_down, wp_down, t, 32, 8); return; }
    t -= 4096;
    if (t < 27648) {   // W (27,32,32): Wp[((k*4+q)*32+n)*8+j] = W[k][q*8+j][n]
        int j = t & 7, n = (t >> 3) & 31, q = (t >> 8) & 3, k = t >> 10;
        wp_r0[t] = f2b(W_r0[(k * 32 + q * 8 + j) * 32 + n]); return;
    }
    t -= 27648;
    if (t < 27648) {
        int j = t & 7, n = (t >> 3) & 31, q = (t >> 8) & 3, k = t >> 10;
        wp_r1[t] = f2b(W_r1[(k * 32 + q * 8 + j) * 32 + n]); return;
    }
    t -= 27648;
    if (t < 27648) {
        int j = t & 7, n = (t >> 3) & 31, q = (t >> 8) & 3, k = t >> 10;
        wp_fin[t] = f2b(W_fin[(k * 32 + q * 8 + j) * 32 + n]); return;
    }
    t -= 27648;
    if (t < 16) p0[t] = 0;
    else if (t < 32) p1[t - 16] = 0;
    else if (t < 64) p2[t - 32] = 0;
    else if (t < 96) p3[t - 64] = 0;
    else if (t < 128) p4[t - 96] = 0;
}

// first conv: C_IN=1 -> 16, K=27, relu; writes f32 (cached out) + bf16 copy
__global__ __launch_bounds__(TPB) void conv_first_k(
    const float* __restrict__ xin, const float* __restrict__ W,
    const float* __restrict__ b, const int* __restrict__ tab, long long rowcap,
    int n0, float* __restrict__ outf, unsigned short* __restrict__ outb) {
    int j = blockIdx.x * blockDim.x + threadIdx.x;
    if (j >= n0) return;
    float acc[16];
#pragma unroll
    for (int c = 0; c < 16; ++c) acc[c] = b[c];
#pragma unroll
    for (int k = 0; k < 27; ++k) {
        int idx = tab[(long long)k * rowcap + j];
        bool ok = (unsigned)idx < (unsigned)n0;
        int cidx = ok ? idx : 0;
        float v = xin[cidx];
        v = ok ? v : 0.f;
        const float* Wk = W + k * 16;
#pragma unroll
        for (int c = 0; c < 16; ++c) acc[c] = fmaf(v, Wk[c], acc[c]);
    }
    float* orow = outf + (long long)j * 16;
    unsigned short* brow = outb + (long long)j * 16;
#pragma unroll
    for (int c = 0; c < 16; ++c) {
        float v = fmaxf(acc[c], 0.f);
        orow[c] = v;
        brow[c] = f2b(v);
    }
}

// K-chunk body: steps [SB,SE) over all 4 subtiles. Phase 1 issues ALL idx
// loads of the chunk independently (one round-trip); phase 2 runs the
// gather+MFMA loop software-pipelined one step ahead.
template <int CIN, int COUT, int NT, int SB, int SE>
static __device__ __forceinline__ void kchunk(
    const unsigned short* __restrict__ xb, const unsigned short* __restrict__ Wp,
    const int* __restrict__ tab, long long rowcap, int n_in,
    long long j0, int m, int q, int coff, floatx4 (&acc)[4][NT]) {
    constexpr int NS = SE - SB;
    if (NS <= 0) return;
    int idx[NS > 0 ? NS : 1][4];
#pragma unroll
    for (int s = 0; s < NS; ++s) {           // phase 1: all idx loads in flight
        const int ks = (CIN == 32) ? (SB + s) : 2 * (SB + s) + (q >> 1);
        const int* trow = tab + (long long)ks * rowcap + j0 + m;
#pragma unroll
        for (int t = 0; t < 4; ++t) {
            unsigned v = (unsigned)trow[16 * t];
            idx[s][t] = (int)(v < (unsigned)n_in ? v : (unsigned)n_in);  // poison/pad -> zero
        }
    }
    short8 cur[4];
#pragma unroll
    for (int t = 0; t < 4; ++t)
        cur[t] = *(const short8*)(xb + (long long)idx[0][t] * CIN + coff);
#pragma unroll
    for (int s = 0; s < NS; ++s) {           // phase 2: pipelined gather+MFMA
        short8 nxt[4];
        if (s + 1 < NS) {
#pragma unroll
            for (int t = 0; t < 4; ++t)      // next step's gathers issue BEFORE
                nxt[t] = *(const short8*)(xb + (long long)idx[s + 1][t] * CIN + coff);
        }
        short8 b0 = *(const short8*)(Wp + ((((SB + s) * 4 + q) * COUT) + m) * 8);
        short8 b1;
        if (NT == 2) b1 = *(const short8*)(Wp + ((((SB + s) * 4 + q) * COUT) + 16 + m) * 8);
#pragma unroll
        for (int t = 0; t < 4; ++t) {
            acc[t][0] = __builtin_amdgcn_mfma_f32_16x16x32_bf16(cur[t], b0, acc[t][0], 0, 0, 0);
            if (NT == 2)
                acc[t][1] = __builtin_amdgcn_mfma_f32_16x16x32_bf16(cur[t], b1, acc[t][1], 0, 0, 0);
        }
        if (s + 1 < NS) {
#pragma unroll
            for (int t = 0; t < 4; ++t) cur[t] = nxt[t];
        }
    }
}

// MFMA conv, K-SPLIT: block = one 64-row tile; wave wv computes K-steps
// [STEPS*wv/4, STEPS*(wv+1)/4) for ALL 4 subtiles, then the 4 partial
// accumulator sets are reduced through LDS; wave wv owns subtile wv's final
// sum + epilogue. Grid = pad8(ntiles) blocks (XCD-swizzled).
template <int CIN, int COUT, int STEPS, bool RELU, bool RES, bool WF32, bool WB16>
__global__ __launch_bounds__(TPB, 4) void conv_mfma(
    const unsigned short* __restrict__ xb,   // (n_in+1, CIN) bf16, pad row zero
    const unsigned short* __restrict__ Wp,   // packed bf16 fragments
    const float* __restrict__ bias,
    const int* __restrict__ tab, long long rowcap, int n_in, int n_out,
    long long ntiles,
    const unsigned short* __restrict__ resb,
    float* __restrict__ outf, unsigned short* __restrict__ outb) {
    constexpr int NT = COUT / 16;
    // 12 slots: (writer wave w, subtile t), w != t. Layout [nt][slot*64+lane]
    // -> 16B lane stride = 2-way bank aliasing (free).
    __shared__ floatx4 red[NT][12 * 64];
    // bijective XCD swizzle: gridDim.x % 8 == 0, runs = gridDim.x/8
    int runs = (int)gridDim.x >> 3;
    long long tile = (long long)((blockIdx.x & 7) * runs + (blockIdx.x >> 3));
    if (tile >= ntiles) return;              // uniform across block
    int wv = (int)((threadIdx.x >> 6) & 3);  // this wave's K-chunk / subtile id
    int lane = (int)threadIdx.x & 63;
    int m = lane & 15, q = lane >> 4;
    long long j0 = tile * 64;

    floatx4 acc[4][NT];
#pragma unroll
    for (int t = 0; t < 4; ++t)
#pragma unroll
        for (int nt = 0; nt < NT; ++nt) acc[t][nt] = floatx4{0.f, 0.f, 0.f, 0.f};

    const int coff = (CIN == 32) ? q * 8 : (q & 1) * 8;
    constexpr int C1 = STEPS / 4, C2 = STEPS / 2, C3 = (3 * STEPS) / 4;
    if (wv == 0)
        kchunk<CIN, COUT, NT, 0, C1>(xb, Wp, tab, rowcap, n_in, j0, m, q, coff, acc);
    else if (wv == 1)
        kchunk<CIN, COUT, NT, C1, C2>(xb, Wp, tab, rowcap, n_in, j0, m, q, coff, acc);
    else if (wv == 2)
        kchunk<CIN, COUT, NT, C2, C3>(xb, Wp, tab, rowcap, n_in, j0, m, q, coff, acc);
    else
        kchunk<CIN, COUT, NT, C3, STEPS>(xb, Wp, tab, rowcap, n_in, j0, m, q, coff, acc);

    // stage the 3 foreign-subtile partials (static t indexing; rule-#20-safe)
#pragma unroll
    for (int t = 0; t < 4; ++t) {
        if (t != wv) {
            int sl = wv * 3 + (t > wv ? t - 1 : t);
#pragma unroll
            for (int nt = 0; nt < NT; ++nt)
                red[nt][sl * 64 + lane] = acc[t][nt];
        }
    }
    // own subtile partial -> own[] via static-index selects
    floatx4 own[NT];
#pragma unroll
    for (int nt = 0; nt < NT; ++nt) own[nt] = acc[0][nt];
#pragma unroll
    for (int t = 1; t < 4; ++t)
#pragma unroll
        for (int nt = 0; nt < NT; ++nt)
            if (wv == t) own[nt] = acc[t][nt];
    __syncthreads();
#pragma unroll
    for (int w = 0; w < 4; ++w) {
        if (w != wv) {
            int sl = w * 3 + (wv > w ? wv - 1 : wv);
#pragma unroll
            for (int nt = 0; nt < NT; ++nt)
                own[nt] += red[nt][sl * 64 + lane];
        }
    }

    float bs[2];
    bs[0] = bias[m];
    if (NT == 2) bs[1] = bias[16 + m];
    long long jb = j0 + wv * 16;             // this wave's 16 output rows
#pragma unroll
    for (int u = 0; u < 4; ++u) {
        long long r = jb + q * 4 + u;        // C/D: row=(lane>>4)*4+reg
        if (r < n_out) {
#pragma unroll
            for (int nt = 0; nt < NT; ++nt) {
                float v = own[nt][u] + bs[nt];
                if (RES) v += b2f(resb[r * COUT + nt * 16 + m]);
                if (RELU) v = fmaxf(v, 0.f);
                if (WF32) outf[r * COUT + nt * 16 + m] = v;
                if (WB16) outb[r * COUT + nt * 16 + m] = f2b(v);
            }
        }
    }
}

static inline unsigned nblk(long long n, int b) { return (unsigned)((n + b - 1) / b); }
static inline unsigned pad8(unsigned g) { return ((g + 7) / 8) * 8; }
static inline size_t align64(size_t x) { return (x + 63) & ~(size_t)63; }

extern "C" void kernel_launch(void* const* d_in, const int* in_sizes, int n_in_cnt,
                              void* d_out, int out_size, void* d_ws, size_t ws_size,
                              hipStream_t stream) {
    const float* in_feats = (const float*)d_in[0];
    const float* W_first = (const float*)d_in[1];
    const float* b_first = (const float*)d_in[2];
    const float* W_pre   = (const float*)d_in[3];
    const float* b_pre   = (const float*)d_in[4];
    const float* W_down  = (const float*)d_in[5];
    const float* b_down  = (const float*)d_in[6];
    const float* W_r0    = (const float*)d_in[7];
    const float* b_r0    = (const float*)d_in[8];
    const float* W_r1    = (const float*)d_in[9];
    const float* b_r1    = (const float*)d_in[10];
    const float* W_fin   = (const float*)d_in[11];
    const float* b_fin   = (const float*)d_in[12];
    const int* km0_in  = (const int*)d_in[13];
    const int* km0_out = (const int*)d_in[14];
    const int* kmd_in  = (const int*)d_in[15];
    const int* kmd_out = (const int*)d_in[16];
    const int* km1_in  = (const int*)d_in[17];
    const int* km1_out = (const int*)d_in[18];

    const int n0 = in_sizes[0];
    const int n1 = (out_size - 16 * n0) / 32;
    const long long P0 = in_sizes[13] / 27;
    const long long Pd = in_sizes[15] / 8;
    const long long P1 = in_sizes[17] / 27;

    // rowcap: multiple of 64 covering n+1 (pad slot); T = rc/64 tiles
    const long long rc0 = ((n0 + 64) / 64) * 64;
    const long long rc1 = ((n1 + 64) / 64) * 64;
    const int T0 = (int)(rc0 / 64), T1 = (int)(rc1 / 64);

    float* out_lo = (float*)d_out;                 // (n1,32)
    float* cached = out_lo + (size_t)n1 * 32;      // (n0,16) f32

    char* base = (char*)d_ws;
    size_t off = 0;
    auto alloc = [&](size_t bytes) { void* p = base + off; off = align64(off + bytes); return p; };
    int* t0 = (int*)alloc(sizeof(int) * 28 * rc0);     // 27 rows + pad ks=27 (poison->clamp)
    int* t1 = (int*)alloc(sizeof(int) * 27 * rc1);
    int* td = (int*)alloc(sizeof(int) * 8 * rc1);
    int* st0 = (int*)alloc(sizeof(int) * 27 * (T0 + 1));
    int* st1 = (int*)alloc(sizeof(int) * 27 * (T1 + 1));
    unsigned short* c0b   = (unsigned short*)alloc(sizeof(short) * 16 * (n0 + 1));
    unsigned short* x0pre = (unsigned short*)alloc(sizeof(short) * 16 * (n0 + 1));
    unsigned short* x1a   = (unsigned short*)alloc(sizeof(short) * 32 * (n1 + 1));
    unsigned short* x1b   = (unsigned short*)alloc(sizeof(short) * 32 * (n1 + 1));
    unsigned short* x1c   = (unsigned short*)alloc(sizeof(short) * 32 * (n1 + 1));
    unsigned short* wp_pre  = (unsigned short*)alloc(sizeof(short) * 14 * 4 * 16 * 8);
    unsigned short* wp_down = (unsigned short*)alloc(sizeof(short) * 4 * 4 * 32 * 8);
    unsigned short* wp_r0   = (unsigned short*)alloc(sizeof(short) * 27 * 1024);
    unsigned short* wp_r1   = (unsigned short*)alloc(sizeof(short) * 27 * 1024);
    unsigned short* wp_fin  = (unsigned short*)alloc(sizeof(short) * 27 * 1024);
    (void)ws_size; (void)n_in_cnt;

    // CSR window tables
    const long long searchN = 27LL * (T0 + 1) + 27LL * (T1 + 1);
    search_k<<<nblk(searchN, TPB), TPB, 0, stream>>>(
        km0_out, km1_out, P0, P1, T0, T1, n0, n1, st0, st1);

    // dense tab build (full-line stores; replaces the random scatter)
    {
        int Tm = T0 > T1 ? T0 : T1;
        dim3 tg(nblk(Tm, 4), 54);
        tabgen<<<tg, TPB, 0, stream>>>(km0_in, km0_out, km1_in, km1_out,
                                       st0, st1, t0, t1, P0, P1, T0, T1, n0, n1);
    }

    // td scatter + weight packing + pad-row zeroing (td: NO fill — poison
    // slots >= n_in clamp to the zero row in the down conv)
    const long long prepN = 8 * Pd + 7168 + 4096 + 3 * 27648 + 128;
    prep_all<<<nblk(prepN, TPB), TPB, 0, stream>>>(
        kmd_in, kmd_out, td, (unsigned)Pd, (unsigned)rc1, (unsigned)n1,
        W_pre, W_down, W_r0, W_r1, W_fin,
        wp_pre, wp_down, wp_r0, wp_r1, wp_fin,
        c0b + (size_t)n0 * 16, x0pre + (size_t)n0 * 16,
        x1a + (size_t)n1 * 32, x1b + (size_t)n1 * 32, x1c + (size_t)n1 * 32);

    // first: 1 -> 16, relu -> cached (f32) + c0b (bf16)
    conv_first_k<<<nblk(n0, TPB), TPB, 0, stream>>>(in_feats, W_first, b_first, t0, rc0,
                                                    n0, cached, c0b);
    // K-split convs: one 64-row tile per 256-thread block (4 waves split K)
    const unsigned g0 = pad8((unsigned)T0), g1 = pad8((unsigned)T1);
    // pre: 16 -> 16 relu; 14 paired steps cover 27 offsets (+poison row 27)
    conv_mfma<16, 16, 14, true, false, false, true><<<g0, TPB, 0, stream>>>(
        c0b, wp_pre, b_pre, t0, rc0, n0, n0, T0, nullptr, nullptr, x0pre);
    // down: 16 -> 32 relu; 4 paired steps cover 8 offsets
    conv_mfma<16, 32, 4, true, false, false, true><<<g1, TPB, 0, stream>>>(
        x0pre, wp_down, b_down, td, rc1, n0, n1, T1, nullptr, nullptr, x1a);
    // r0: 32 -> 32 relu
    conv_mfma<32, 32, 27, true, false, false, true><<<g1, TPB, 0, stream>>>(
        x1a, wp_r0, b_r0, t1, rc1, n1, n1, T1, nullptr, nullptr, x1b);
    // r1: 32 -> 32 + residual x1a, no relu
    conv_mfma<32, 32, 27, false, true, false, true><<<g1, TPB, 0, stream>>>(
        x1b, wp_r1, b_r1, t1, rc1, n1, n1, T1, x1a, nullptr, x1c);
    // fin: 32 -> 32 -> d_out (f32)
    conv_mfma<32, 32, 27, false, false, true, false><<<g1, TPB, 0, stream>>>(
        x1c, wp_fin, b_fin, t1, rc1, n1, n1, T1, nullptr, out_lo, nullptr);
}